// Round 6
// baseline (75.585 us; speedup 1.0000x reference)
//
#include <hip/hip_runtime.h>

#define L_SEQ   512
#define NHEADS_ 8
#define HEADDIM_ 128
#define QKD     16
#define DINNER  1024
#define EPS_F   1e-3f
#define STD_F   0.0078125f   // 1/sqrt(2*512*16) = 1/128

// LDS layout for KS[t_local][l]: addr = t*KS_ROW + (l>>5)*33 + (l&31)
// KS_ROW=529 (529%32=17); phase-A stores and phase-B reads both <=2-way (free).
#define KS_ROW  529

typedef __attribute__((ext_vector_type(8))) short  short8;
typedef __attribute__((ext_vector_type(4))) float  floatx4;
typedef __attribute__((ext_vector_type(2))) float  float2v;

// cos(2*pi*rev): v_cos_f32 takes revolutions; reduce to [0,1) first.
__device__ __forceinline__ float cosrev(float rev) {
    float r = rev - floorf(rev);
    return __builtin_amdgcn_cosf(r);
}

// 2*cos(2*pi*a) for tiny |a| (<= ~0.008 rev): even poly, err ~2e-12.
__device__ __forceinline__ float two_cos_small(float a) {
    float x = a * a;
    return fmaf(fmaf(x, 129.8787876f, -39.4784176f), x, 2.0f);
}

// float -> bf16 bits, round-to-nearest-even (for vtrans)
__device__ __forceinline__ unsigned short f2bf_rne(float x) {
    union { float f; unsigned int u; } v;
    v.f = x;
    unsigned int r = v.u + 0x7fffu + ((v.u >> 16) & 1u);
    return (unsigned short)(r >> 16);
}

// 8 floats -> short8 bf16 via v_cvt_pk_bf16_f32 (RNE, 2 floats/inst).
__device__ __forceinline__ short8 pack_bf16x8(const float* s) {
    union { int i[4]; short8 v; } u;
#pragma unroll
    for (int p = 0; p < 4; ++p)
        asm("v_cvt_pk_bf16_f32 %0, %1, %2"
            : "=v"(u.i[p]) : "v"(s[2 * p]), "v"(s[2 * p + 1]));
    return u.v;
}

// sum of 8 float2v, then horizontal add
__device__ __forceinline__ float tree8(const float2v* C) {
    float2v s = ((C[0] + C[1]) + (C[2] + C[3])) + ((C[4] + C[5]) + (C[6] + C[7]));
    return s.x + s.y;
}

// Kernel 1: vt layout [bn][lchunk=l>>3][h][l&7] bf16 (unchanged from R5).
__global__ __launch_bounds__(256) void vtrans_kernel(const float* __restrict__ v,
                                                     unsigned short* __restrict__ vt) {
    const int bid = blockIdx.x;
    const int tid = threadIdx.x;
    const int l0 = (bid & 7) * 64;
    const int h0 = ((bid >> 3) & 1) * 64;
    const int bn = bid >> 4;
    const int b = bn >> 3, n = bn & 7;
    __shared__ float tile[64][65];
    const float* vb = v + ((size_t)b * L_SEQ) * DINNER + n * HEADDIM_;
    float4 r[4];
#pragma unroll
    for (int i = 0; i < 4; ++i) {
        int f = i * 256 + tid;
        int hq = f & 15, ll = f >> 4;
        r[i] = *(const float4*)(vb + (size_t)(l0 + ll) * DINNER + (h0 + hq * 4));
    }
#pragma unroll
    for (int i = 0; i < 4; ++i) {
        int f = i * 256 + tid;
        int hq = f & 15, ll = f >> 4;
        tile[hq * 4 + 0][ll] = r[i].x;
        tile[hq * 4 + 1][ll] = r[i].y;
        tile[hq * 4 + 2][ll] = r[i].z;
        tile[hq * 4 + 3][ll] = r[i].w;
    }
    __syncthreads();
    unsigned short* vdst = vt + (size_t)bn * (64 * 128 * 8);
#pragma unroll
    for (int i = 0; i < 2; ++i) {
        int f = i * 256 + tid;
        int hh = f & 63;
        int lc = f >> 6;
        short8 pk;
#pragma unroll
        for (int j = 0; j < 8; ++j)
            pk[j] = (short)f2bf_rne(tile[hh][lc * 8 + j]);
        *(short8*)(vdst + ((size_t)((l0 >> 3) + lc) * 128 + (h0 + hh)) * 8) = pk;
    }
}

// Kernel 2: COMPACT-CODE restructure. Evidence: wave stall ~85% (R3: VALUBusy
// 12.3% @44us), insensitive to 2x TLP (R4) and to data prefetch (R5) -- the
// shared trait of all variants is ~20 KB of fully-unrolled straight-line code
// (zero I$ reuse; every inst streamed from L2). This version ROLLS the phase-A
// m-loop (8 iters x 2 Chebyshev steps, X/Y ping-pong: no copies, no dynamic
// indexing) and the phase-B c-loop (4 iters; jj unrolled inside; bfr in named
// vars; loop-carried pointer increments). Hot code ~20 KB -> ~6 KB.
__global__ __launch_bounds__(256, 2) void vand_fused(const float* __restrict__ v,
                                                     const float* __restrict__ q,
                                                     const float* __restrict__ k,
                                                     const unsigned short* __restrict__ vt,
                                                     float* __restrict__ out) {
    const int tid  = threadIdx.x;
    const int w    = tid >> 6;
    const int lane = tid & 63;
    const int tl   = lane & 15;
    const int quad = lane >> 4;
    const int ttile = blockIdx.x;     // 0..31
    const int bn    = blockIdx.y;     // 0..15
    const int b = bn >> 3, n = bn & 7;
    const float t0f = (float)(ttile * 16);

    __shared__ float smem[16 * KS_ROW];   // 33.9 KB: ksl (A/B), red (epilogue)
    float* ksl = smem;

    // ---- top-of-kernel prefetch (addresses all entry-known) ----
    float4 kf[2][4];
#pragma unroll
    for (int rep = 0; rep < 2; ++rep) {
        const int l = w * 128 + rep * 64 + lane;
        const float* krow = k + ((size_t)(b * L_SEQ + l)) * (NHEADS_ * QKD) + n * QKD;
#pragma unroll
        for (int d4 = 0; d4 < 4; ++d4)
            kf[rep][d4] = *(const float4*)(krow + 4 * d4);
    }
    const int t = ttile * 16 + tl;
    const float* qrow = q + ((size_t)(b * L_SEQ + t)) * (NHEADS_ * QKD) + n * QKD;
    float4 qf[4];
#pragma unroll
    for (int d4 = 0; d4 < 4; ++d4)
        qf[d4] = *(const float4*)(qrow + 4 * d4);
    const float* vbase = v + ((size_t)b * L_SEQ) * DINNER + n * HEADDIM_;
    float4 vres[2];
    size_t gis[2];
#pragma unroll
    for (int i = 0; i < 2; ++i) {
        int g    = i * 256 + tid;
        int hb   = g & 31;
        int tloc = g >> 5;
        gis[i] = (size_t)(ttile * 16 + tloc) * DINNER + hb * 4;
        vres[i] = *(const float4*)(vbase + gis[i]);
    }

    // ---- Phase A: KS rows for this wave's 128-l range (rep unrolled x2,
    //      m-loop ROLLED: 8 iters x 2 steps, X/Y ping-pong) ----
#pragma unroll
    for (int rep = 0; rep < 2; ++rep) {
        const int l = w * 128 + rep * 64 + lane;
        float kk[16];
#pragma unroll
        for (int d4 = 0; d4 < 4; ++d4) {
            kk[d4 * 4 + 0] = kf[rep][d4].x; kk[d4 * 4 + 1] = kf[rep][d4].y;
            kk[d4 * 4 + 2] = kf[rep][d4].z; kk[d4 * 4 + 3] = kf[rep][d4].w;
        }
        float2v M2[8], X[8], Y[8];   // X = C_{m-1}, Y = C_m
#pragma unroll
        for (int i = 0; i < 8; ++i) {
            float a0 = EPS_F * kk[2 * i], a1 = EPS_F * kk[2 * i + 1];
            M2[i].x = two_cos_small(a0);        M2[i].y = two_cos_small(a1);
            Y[i].x = cosrev(a0 * t0f);          Y[i].y = cosrev(a1 * t0f);
            X[i].x = cosrev(a0 * (t0f - 1.f));  X[i].y = cosrev(a1 * (t0f - 1.f));
        }
        int moff = (l >> 5) * 33 + (l & 31);
#pragma unroll 1
        for (int it = 0; it < 8; ++it) {
            ksl[moff] = tree8(Y);                       // row m = 2*it
#pragma unroll
            for (int i = 0; i < 8; ++i) X[i] = M2[i] * Y[i] - X[i];   // X = C_{m+1}
            ksl[moff + KS_ROW] = tree8(X);              // row m+1
#pragma unroll
            for (int i = 0; i < 8; ++i) Y[i] = M2[i] * X[i] - Y[i];   // Y = C_{m+2}
            moff += 2 * KS_ROW;
        }
    }

    // ---- Phase B init: q recurrence at l0 ----
    const int   l0  = w * 128 + quad * 32;
    const float l0f = (float)l0;
    float2v M2[8], X[8], Y[8];   // X = C_{l-1}, Y = C_l
#pragma unroll
    for (int d4 = 0; d4 < 4; ++d4) {
        float aa[4] = {EPS_F * qf[d4].x, EPS_F * qf[d4].y,
                       EPS_F * qf[d4].z, EPS_F * qf[d4].w};
#pragma unroll
        for (int e = 0; e < 2; ++e) {
            int i = d4 * 2 + e;
            float a0 = aa[2 * e], a1 = aa[2 * e + 1];
            M2[i].x = two_cos_small(a0);        M2[i].y = two_cos_small(a1);
            Y[i].x = cosrev(a0 * l0f);          Y[i].y = cosrev(a1 * l0f);
            X[i].x = cosrev(a0 * (l0f - 1.f));  X[i].y = cosrev(a1 * (l0f - 1.f));
        }
    }

    const unsigned short* vrow = vt + (size_t)bn * (64 * 128 * 8);
    const short* vp = (const short*)vrow + (w * 16 + quad * 4) * 1024 + tl * 8;
    int koff = tl * KS_ROW + (4 * w + quad) * 33;

    floatx4 acc[8] = {};

    // ---- Phase B c-loop: ROLLED (4 iters), jj unrolled w/ ping-pong ----
#pragma unroll 1
    for (int c = 0; c < 4; ++c) {
        // B-fragments for this c: 8 named short8 (no runtime-indexed array)
        short8 b0 = *(const short8*)(vp + 0 * 128);
        short8 b1 = *(const short8*)(vp + 1 * 128);
        short8 b2 = *(const short8*)(vp + 2 * 128);
        short8 b3 = *(const short8*)(vp + 3 * 128);
        short8 b4 = *(const short8*)(vp + 4 * 128);
        short8 b5 = *(const short8*)(vp + 5 * 128);
        short8 b6 = *(const short8*)(vp + 6 * 128);
        short8 b7 = *(const short8*)(vp + 7 * 128);
        float kv[8];
#pragma unroll
        for (int jj = 0; jj < 8; ++jj) kv[jj] = ksl[koff + jj];
        float ss[8];
#pragma unroll
        for (int p = 0; p < 4; ++p) {   // 2 jj per p: Y-step then X-step
            ss[2 * p] = tree8(Y) - kv[2 * p];
#pragma unroll
            for (int i = 0; i < 8; ++i) X[i] = M2[i] * Y[i] - X[i];
            ss[2 * p + 1] = tree8(X) - kv[2 * p + 1];
#pragma unroll
            for (int i = 0; i < 8; ++i) Y[i] = M2[i] * X[i] - Y[i];
        }
        const short8 af = pack_bf16x8(ss);
        acc[0] = __builtin_amdgcn_mfma_f32_16x16x32_bf16(af, b0, acc[0], 0, 0, 0);
        acc[1] = __builtin_amdgcn_mfma_f32_16x16x32_bf16(af, b1, acc[1], 0, 0, 0);
        acc[2] = __builtin_amdgcn_mfma_f32_16x16x32_bf16(af, b2, acc[2], 0, 0, 0);
        acc[3] = __builtin_amdgcn_mfma_f32_16x16x32_bf16(af, b3, acc[3], 0, 0, 0);
        acc[4] = __builtin_amdgcn_mfma_f32_16x16x32_bf16(af, b4, acc[4], 0, 0, 0);
        acc[5] = __builtin_amdgcn_mfma_f32_16x16x32_bf16(af, b5, acc[5], 0, 0, 0);
        acc[6] = __builtin_amdgcn_mfma_f32_16x16x32_bf16(af, b6, acc[6], 0, 0, 0);
        acc[7] = __builtin_amdgcn_mfma_f32_16x16x32_bf16(af, b7, acc[7], 0, 0, 0);
        vp += 1024;
        koff += 8;
    }

    // ---- split-K reduction + epilogue (red overlays ksl; barrier both sides) ----
    __syncthreads();
    float (*red)[64][33] = (float (*)[64][33])smem;   // 4*64*33 = 8448 <= 16*529
#pragma unroll
    for (int ht = 0; ht < 8; ++ht)
#pragma unroll
        for (int r = 0; r < 4; ++r)
            red[w][lane][ht * 4 + r] = acc[ht][r];
    __syncthreads();

    float* obase = out + ((size_t)b * L_SEQ) * DINNER + n * HEADDIM_;
#pragma unroll
    for (int i = 0; i < 2; ++i) {
        int g    = i * 256 + tid;
        int hb   = g & 31;
        int tloc = g >> 5;
        int lidx0 = ((tloc >> 2) << 4) + ((hb & 3) << 2);
        int aidx  = ((hb >> 2) << 2) + (tloc & 3);
        float4 sum;
        float* sp = &sum.x;
#pragma unroll
        for (int e = 0; e < 4; ++e) {
            int lidx = lidx0 + e;
            sp[e] = (red[0][lidx][aidx] + red[1][lidx][aidx])
                  + (red[2][lidx][aidx] + red[3][lidx][aidx]);
        }
        float4 o;
        o.x = fmaf(STD_F, sum.x, vres[i].x);
        o.y = fmaf(STD_F, sum.y, vres[i].y);
        o.z = fmaf(STD_F, sum.z, vres[i].z);
        o.w = fmaf(STD_F, sum.w, vres[i].w);
        *(float4*)(obase + gis[i]) = o;
    }
}

extern "C" void kernel_launch(void* const* d_in, const int* in_sizes, int n_in,
                              void* d_out, int out_size, void* d_ws, size_t ws_size,
                              hipStream_t stream) {
    const float* v = (const float*)d_in[0];
    const float* q = (const float*)d_in[1];
    const float* k = (const float*)d_in[2];
    float* out = (float*)d_out;
    unsigned short* vt = (unsigned short*)d_ws;   // 16*64*128*8 bf16 = 2 MiB

    vtrans_kernel<<<dim3(256), 256, 0, stream>>>(v, vt);
    vand_fused<<<dim3(L_SEQ / 16, 16), 256, 0, stream>>>(v, q, k, vt, out);
}